// Round 11
// baseline (188.874 us; speedup 1.0000x reference)
//
#include <hip/hip_runtime.h>

#define NW 14
#define NL 3
#define NGAT 42            // 3 layers x 14 rotation gates
#define DIM 16384          // 2^14 amplitudes
#define BLOCK 1024

// ---------------------------------------------------------------------------
// Round 22: r21 base (87.7us steady, absmax 1.22e-4, pair0 fused) + PAIR-2
// FUSION (batches 4+5 = layer-1 wires 0-7). This is the bisect step for
// r18's failure: pair2 is the first pair with NON-TRIVIAL frames — basisA/
// basisB are layer-1 C-columns, outer dirs pyd corrected for BOTH groups:
//   d = u ^ sum_j bA_j*par(rA_j&u) ^ sum_k bB_k*par(rB_k&u)
// Biorthogonality par(R_w&C_v)=delta_wv (preserved by CNOT updates, checked)
// makes basisA/basisB cross-corrections vanish. Structure per pair:
//   bar -> build Wa,Wb tables (tid<512) -> 16 scattered reads (frag
//   A[r=eB][k=eA] from F[3]) -> bar -> stage1 mfh(state,Wa)=D1=(Wa*M)^T,
//   pk -> stage2 mfh(Wb,pk(D1)) -> clean b128 store under FQ2=[bB,bA,pyd].
// Batch 6's reader re-pointed at FQ2. All else byte-identical to r21.
// Decision: pass -> r23 fuses pairs 1,3,4; fail -> corrections are the r18
// bug locus, revert to r21.
// ---------------------------------------------------------------------------

typedef float        f4  __attribute__((ext_vector_type(4)));
typedef _Float16     h8  __attribute__((ext_vector_type(8)));
typedef unsigned int u4v __attribute__((ext_vector_type(4)));

constexpr int parity14(int v) { int p = 0; for (int i = 0; i < NW; ++i) p ^= (v >> i) & 1; return p; }
constexpr int hibit(int v) { int h = -1; for (int i = 0; i < NW; ++i) if ((v >> i) & 1) h = i; return h; }

struct Lin { int col[NW]; };

constexpr int lin_apply(const Lin& M, int x) {
    int r = 0;
    for (int i = 0; i < NW; ++i) if ((x >> i) & 1) r ^= M.col[i];
    return r;
}
constexpr Lin lin_inverse(const Lin& M) {
    int E[NW] = {}, P[NW] = {};
    for (int i = 0; i < NW; ++i) {
        int v = M.col[i], p = 1 << i;
        while (v) {
            int h = hibit(v);
            if (!E[h]) { E[h] = v; P[h] = p; break; }
            v ^= E[h]; p ^= P[h];
        }
    }
    Lin R{};
    for (int i = 0; i < NW; ++i) {
        int v = 1 << i, p = 0;
        while (v) { int h = hibit(v); v ^= E[h]; p ^= P[h]; }
        R.col[i] = p;
    }
    return R;
}
constexpr Lin lin_compose(const Lin& A, const Lin& B) {
    Lin R{};
    for (int i = 0; i < NW; ++i) R.col[i] = lin_apply(A, B.col[i]);
    return R;
}

// ---- algorithm structure (frames, cosets, duality corrections) ----
struct Alg {
    int ngates[12];
    int gidx[12][4];
    int basisA[12][4];
    int comboA[12][16];
    int cvecA[12][10];
    Lin F[12];
    int Rf[NW];         // final Z-row masks for the tail features
};

constexpr Alg make_alg() {
    Alg A{};
    int R[NW] = {}, C[NW] = {};
    for (int p = 0; p < NW; ++p) { R[p] = 1 << p; C[p] = 1 << p; }
    int bi = 0;
    for (int l = 0; l < NL; ++l) {
        const int sizes[4] = {4, 4, 4, 2};
        int w0 = 0;
        for (int s = 0; s < 4; ++s) {
            const int ng = sizes[s];
            A.ngates[bi] = ng;
            int basis[4] = {}, rr[4] = {};
            for (int j = 0; j < ng; ++j) {
                int w = w0 + j, p = 13 - w;
                basis[j] = C[p];
                rr[j] = R[p];
                A.gidx[bi][j] = l * NW + w;
            }
            // echelon for independence
            int ech[4] = {}; int ne = 0;
            for (int j = 0; j < ng; ++j) {
                int v = basis[j];
                bool ch = true;
                while (ch) { ch = false;
                    for (int k = 0; k < ne; ++k)
                        if (v && ((v >> hibit(ech[k])) & 1)) { v ^= ech[k]; ch = true; }
                }
                ech[ne++] = v;
            }
            // pad to 4 from null space of gate parity masks
            int nb = ng;
            for (int cand = 1; cand < DIM && nb < 4; ++cand) {
                bool ok = true;
                for (int j = 0; j < ng; ++j) if (parity14(cand & rr[j])) { ok = false; break; }
                if (!ok) continue;
                int v = cand;
                bool ch = true;
                while (ch) { ch = false;
                    for (int k = 0; k < ne; ++k)
                        if (v && ((v >> hibit(ech[k])) & 1)) { v ^= ech[k]; ch = true; }
                }
                if (v) { basis[nb++] = cand; ech[ne++] = v; }
            }
            // pivots & non-pivot positions
            int piv[4] = {};
            for (int k = 0; k < 4; ++k) piv[k] = hibit(ech[k]);
            for (int a = 0; a < 4; ++a)
                for (int b2 = a + 1; b2 < 4; ++b2)
                    if (piv[b2] < piv[a]) { int t = piv[a]; piv[a] = piv[b2]; piv[b2] = t; }
            int npp[10] = {}; int nn = 0;
            for (int bit = 0; bit < NW; ++bit) {
                bool isp = false;
                for (int k = 0; k < 4; ++k) if (piv[k] == bit) isp = true;
                if (!isp) npp[nn++] = bit;
            }
            // duality-corrected coset directions
            for (int k = 0; k < 10; ++k) {
                int c = 1 << npp[k];
                for (int j = 0; j < ng; ++j) if ((rr[j] >> npp[k]) & 1) c ^= basis[j];
                A.cvecA[bi][k] = c;
            }
            for (int e = 0; e < 16; ++e) {
                int v = 0;
                for (int j = 0; j < 4; ++j) if ((e >> j) & 1) v ^= basis[j];
                A.comboA[bi][e] = v;
            }
            for (int j = 0; j < 4; ++j) A.basisA[bi][j] = basis[j];
            for (int j = 0; j < 4; ++j) A.F[bi].col[j] = basis[j];
            for (int k = 0; k < 10; ++k) A.F[bi].col[4 + k] = A.cvecA[bi][k];
            w0 += ng;
            ++bi;
        }
        // CNOT chain (w,w+1) w=0..12 then (13,0)
        for (int w = 0; w < NW; ++w) {
            int c = w, t = (w + 1) % NW;
            int pc = 13 - c, pt = 13 - t;
            R[pt] ^= R[pc];
            C[pc] ^= C[pt];
        }
    }
    for (int p = 0; p < NW; ++p) A.Rf[p] = R[p];
    return A;
}

// ---- pair-0 frames (layer 0: R=C=identity, corrections vanish) ----
constexpr Lin make_fin() {
    Lin F{};
    for (int j = 0; j < 4; ++j) F.col[j]     = 1 << (13 - j);  // bA: C at wire j
    for (int j = 0; j < 4; ++j) F.col[4 + j] = 1 << (9 - j);   // bB: C at wire 4+j
    for (int k = 0; k < 6; ++k) F.col[8 + k] = 1 << (5 - k);   // outer units
    return F;
}
constexpr Lin make_fp0() {
    Lin F{};
    for (int j = 0; j < 4; ++j) F.col[j]     = 1 << (9 - j);
    for (int j = 0; j < 4; ++j) F.col[4 + j] = 1 << (13 - j);
    for (int k = 0; k < 6; ++k) F.col[8 + k] = 1 << (5 - k);
    return F;
}
constexpr Lin FIN = make_fin();
constexpr Lin FP0 = make_fp0();

// ---- pair-2 data (layer 1, wires 0-7): non-trivial frames + corrections ----
struct PairAlg {
    int gA[4]; int gB[4];
    int bA[4]; int bB[4];
    int pyd[6];
    Lin Fout;           // col[0:3]=bB, col[4:7]=bA, col[8:13]=pyd
};

constexpr PairAlg make_pair_l1() {
    int R[NW] = {}, C[NW] = {};
    for (int p = 0; p < NW; ++p) { R[p] = 1 << p; C[p] = 1 << p; }
    // apply layer 0's CNOT chain to reach layer-1 start
    for (int w = 0; w < NW; ++w) {
        int c = w, t = (w + 1) % NW;
        int pc = 13 - c, pt = 13 - t;
        R[pt] ^= R[pc];
        C[pc] ^= C[pt];
    }
    PairAlg P{};
    int rA[4] = {}, rB[4] = {};
    for (int j = 0; j < 4; ++j) {
        int p = 13 - j;                  // wires 0..3
        P.bA[j] = C[p]; rA[j] = R[p];
        P.gA[j] = 1 * NW + j;
    }
    for (int j = 0; j < 4; ++j) {
        int p = 13 - (4 + j);            // wires 4..7
        P.bB[j] = C[p]; rB[j] = R[p];
        P.gB[j] = 1 * NW + 4 + j;
    }
    // echelon of the 8 tile-basis vectors -> pivots
    int ech[8] = {}; int ne = 0;
    for (int s = 0; s < 8; ++s) {
        int v = (s < 4) ? P.bA[s] : P.bB[s - 4];
        bool ch = true;
        while (ch) { ch = false;
            for (int k = 0; k < ne; ++k)
                if (v && ((v >> hibit(ech[k])) & 1)) { v ^= ech[k]; ch = true; }
        }
        ech[ne++] = v;
    }
    int piv[8] = {};
    for (int k = 0; k < 8; ++k) piv[k] = hibit(ech[k]);
    int nn = 0;
    for (int bit = 0; bit < NW && nn < 6; ++bit) {
        bool isp = false;
        for (int k = 0; k < 8; ++k) if (piv[k] == bit) isp = true;
        if (!isp) {
            // outer dir corrected for BOTH groups (zero m-parity vs rA and rB)
            int u = 1 << bit, d = u;
            for (int j = 0; j < 4; ++j) if (parity14(rA[j] & u)) d ^= P.bA[j];
            for (int j = 0; j < 4; ++j) if (parity14(rB[j] & u)) d ^= P.bB[j];
            P.pyd[nn++] = d;
        }
    }
    for (int j = 0; j < 4; ++j) P.Fout.col[j]     = P.bB[j];
    for (int j = 0; j < 4; ++j) P.Fout.col[4 + j] = P.bA[j];
    for (int k = 0; k < 6; ++k) P.Fout.col[8 + k] = P.pyd[k];
    return P;
}
constexpr PairAlg P2A = make_pair_l1();

// ---- compile-time bank-conflict twist search (b32 rank-5 model) ----
struct Twist { unsigned t[10]; };

constexpr int rankv(const int* v, int nv, int width) {
    int basis[8] = {};
    int rk = 0;
    for (int i = 0; i < nv; ++i) {
        int x = v[i] & ((1 << width) - 1);
        for (int b = width - 1; b >= 0; --b) {
            if (!((x >> b) & 1)) continue;
            if (basis[b]) { x ^= basis[b]; continue; }
            basis[b] = x; ++rk; break;
        }
    }
    return rk;
}

constexpr int img5(int u, const unsigned* t) {
    int r = u & 31;
    for (int k = 0; k < 10; ++k) if ((u >> (4 + k)) & 1) r ^= (int)t[k];
    return r;
}

// readers: b2(FP0), b3(F2), pair2(F3), b6(FQ2), b7..b11(F[r-1]) = 10 patterns
constexpr int eval5(const unsigned* t, const int (*preR)[5], const int* preS) {
    {
        int w[4] = { 4 ^ (int)((t[0] >> 2) & 7), (int)((t[1] >> 2) & 7),
                     (int)((t[2] >> 2) & 7), (int)((t[3] >> 2) & 7) };
        if (rankv(w, 4, 3) < 3) return -1;
    }
    int sc = 0;
    for (int r = 0; r < 10; ++r) {
        int v[5];
        for (int i = 0; i < 5; ++i) v[i] = img5(preR[r][i], t);
        sc += rankv(v, 5, 5);
    }
    {
        int v[5];
        for (int i = 0; i < 5; ++i) v[i] = img5(preS[i], t);
        sc += rankv(v, 5, 5);
    }
    return sc;   // max 11*5 = 55
}

constexpr Twist find_twist() {
    Alg A = make_alg();
    int preR[10][5] = {};
    int idx = 0;
    {   // batch 2 reads FP0
        Lin Fi = lin_inverse(FP0);
        for (int k = 0; k < 4; ++k) preR[idx][k] = lin_apply(Fi, A.cvecA[2][k]);
        preR[idx][4] = lin_apply(Fi, A.basisA[2][2]); ++idx;
    }
    {   // batch 3 reads F[2]
        Lin Fi = lin_inverse(A.F[2]);
        for (int k = 0; k < 4; ++k) preR[idx][k] = lin_apply(Fi, A.cvecA[3][k]);
        preR[idx][4] = lin_apply(Fi, A.basisA[3][2]); ++idx;
    }
    {   // pair2 reads F[3]: lane dirs = bB, bA[2]
        Lin Fi = lin_inverse(A.F[3]);
        for (int k = 0; k < 4; ++k) preR[idx][k] = lin_apply(Fi, P2A.bB[k]);
        preR[idx][4] = lin_apply(Fi, P2A.bA[2]); ++idx;
    }
    {   // batch 6 reads FQ2
        Lin Fi = lin_inverse(P2A.Fout);
        for (int k = 0; k < 4; ++k) preR[idx][k] = lin_apply(Fi, A.cvecA[6][k]);
        preR[idx][4] = lin_apply(Fi, A.basisA[6][2]); ++idx;
    }
    for (int r = 7; r < 12; ++r) {   // batches 7..11 read F[r-1]
        Lin Fi = lin_inverse(A.F[r - 1]);
        for (int k = 0; k < 4; ++k) preR[idx][k] = lin_apply(Fi, A.cvecA[r][k]);
        preR[idx][4] = lin_apply(Fi, A.basisA[r][2]); ++idx;
    }
    int preS[5] = {};
    {
        Lin F0i = lin_inverse(FIN);
        for (int k = 0; k < 5; ++k) preS[k] = lin_apply(F0i, 1 << (k + 2));
    }
    Twist best{};
    for (int k = 0; k < 10; ++k) best.t[k] = 0;
    int bs = eval5(best.t, preR, preS);
    unsigned x = 0x9E3779B9u;
    for (int s = 0; s < 2; ++s) {
        Twist cur{};
        if (s == 0) {
            for (int k = 0; k < 10; ++k) cur.t[k] = 0;
        } else {
            for (int k = 0; k < 10; ++k) {
                x = x * 1664525u + 1013904223u;
                const unsigned m = (k == 0) ? 3u : 7u;
                cur.t[k] = ((x >> 13) & m) << 2;
            }
        }
        int cs = eval5(cur.t, preR, preS);
        for (int pass = 0; pass < 2; ++pass) {
            for (int k = 0; k < 10; ++k) {
                unsigned bc = cur.t[k];
                int bv = cs;
                const unsigned lim = (k == 0) ? 16u : 32u;   // t0: bits[3:2] only
                for (unsigned c = 0; c < lim; c += 4) {
                    cur.t[k] = c;
                    const int e = eval5(cur.t, preR, preS);
                    if (e > bv) { bv = e; bc = c; }
                }
                cur.t[k] = bc;
                cs = bv;
            }
        }
        if (cs > bs) { bs = cs; best = cur; }
    }
    return best;
}

constexpr Twist TW = find_twist();

struct BatchP {
    int ngates;
    int gidx[4];
    unsigned rdy[10];   // byte: 4 * Lambda(cvec[k])  (y-bit directions)
    unsigned rde[16];   // byte: 4 * Lambda(combo[e]) (e-directions)
};
struct Pair2P {
    int gA[4]; int gB[4];
    unsigned rdy[10];   // [0:3]=Lw(bB) (n), [4:5]=Lw(pyd01) (t), [6:9]=Lw(pyd2345) (wid)
    unsigned rde[16];   // Lw(combos of bA): [4]=bA2, [8]=bA3 feed q-part
};
struct PlanP {
    BatchP b[12];
    Pair2P p2;
    unsigned stB[14];   // staging: byte 4 * (T o FIN^-1)(1<<bit)
    unsigned ykey[14];  // tail: parity mask over key = y | (q<<10)
    int zsel[14];       // tail: Walsh index from basis[0,1] parities
    unsigned tw[10];    // T twist columns (idx units, multiples of 4)
};

constexpr PlanP make_planp() {
    Alg A = make_alg();
    PlanP P{};
    for (int bi = 0; bi < 12; ++bi) {
        P.b[bi].ngates = A.ngates[bi];
        for (int j = 0; j < 4; ++j) P.b[bi].gidx[j] = A.gidx[bi][j];
    }
    // T: packed(e, y) -> idx = e ^ (y<<4) ^ twist(y)
    Lin T{};
    for (int j = 0; j < 4; ++j) T.col[j] = 1 << j;
    for (int k = 0; k < 10; ++k) T.col[4 + k] = (1 << (4 + k)) ^ (int)TW.t[k];

    // staging uses FIN
    {
        Lin L0 = lin_compose(T, lin_inverse(FIN));
        for (int bit = 0; bit < NW; ++bit) P.stB[bit] = (unsigned)lin_apply(L0, 1 << bit) * 4u;
    }
    // batches: 2 reads FP0; 3 reads F[2]; 6 reads FQ2; 7..11 read F[r-1]
    for (int r = 2; r < 12; ++r) {
        if (r == 4 || r == 5) continue;   // fused into pair2
        Lin Fprev = (r == 2) ? FP0 : (r == 6) ? P2A.Fout : A.F[r - 1];
        Lin Lw = lin_compose(T, lin_inverse(Fprev));
        for (int k = 0; k < 10; ++k) P.b[r].rdy[k] = (unsigned)lin_apply(Lw, A.cvecA[r][k]) * 4u;
        for (int e = 0; e < 16; ++e) P.b[r].rde[e] = (unsigned)lin_apply(Lw, A.comboA[r][e]) * 4u;
    }
    // pair2 reader (from F[3])
    {
        Lin Lw = lin_compose(T, lin_inverse(A.F[3]));
        for (int j = 0; j < 4; ++j) { P.p2.gA[j] = P2A.gA[j]; P.p2.gB[j] = P2A.gB[j]; }
        for (int k = 0; k < 4; ++k) P.p2.rdy[k] = (unsigned)lin_apply(Lw, P2A.bB[k]) * 4u;
        P.p2.rdy[4] = (unsigned)lin_apply(Lw, P2A.pyd[0]) * 4u;
        P.p2.rdy[5] = (unsigned)lin_apply(Lw, P2A.pyd[1]) * 4u;
        for (int k = 0; k < 4; ++k) P.p2.rdy[6 + k] = (unsigned)lin_apply(Lw, P2A.pyd[2 + k]) * 4u;
        for (int e = 0; e < 16; ++e) {
            int v = 0;
            for (int j = 0; j < 4; ++j) if ((e >> j) & 1) v ^= P2A.bA[j];
            P.p2.rde[e] = (unsigned)lin_apply(Lw, v) * 4u;
        }
    }
    for (int w = 0; w < NW; ++w) {
        int zrw = A.Rf[13 - w];
        unsigned ym = 0;
        for (int k = 0; k < 10; ++k) ym |= (unsigned)parity14(A.cvecA[11][k] & zrw) << k;
        int qm = parity14(A.basisA[11][2] & zrw) | (parity14(A.basisA[11][3] & zrw) << 1);
        P.ykey[w] = ym | ((unsigned)qm << 10);
        P.zsel[w] = parity14(A.basisA[11][0] & zrw) | (parity14(A.basisA[11][1] & zrw) << 1);
    }
    for (int k = 0; k < 10; ++k) P.tw[k] = TW.t[k];
    return P;
}

constexpr PlanP PL = make_planp();

// per-tile byte offsets: t-bits are y-bits 4,5 -> idx bits 8,9 -> byte<<2,
// plus their twist columns (idx units -> byte = idx<<2)
constexpr unsigned TILE_OFF[4] = {
    0u,
    (1u << 10) ^ (PL.tw[4] << 2),
    (1u << 11) ^ (PL.tw[5] << 2),
    (1u << 10) ^ (1u << 11) ^ ((PL.tw[4] ^ PL.tw[5]) << 2)
};

// fp32 (r,i) -> packed f16 dword, round-to-nearest-even (unbiased)
__device__ __forceinline__ unsigned pk_rn(float r, float i) {
    const unsigned hr = (unsigned)__builtin_bit_cast(unsigned short, (_Float16)r);
    const unsigned hi = (unsigned)__builtin_bit_cast(unsigned short, (_Float16)i);
    return hr | (hi << 16);
}
// packed f16 dword -> fp32 (r,i)
__device__ __forceinline__ float2 up(unsigned d) {
    float2 c;
    c.x = (float)__builtin_bit_cast(_Float16, (unsigned short)(d & 0xffffu));
    c.y = (float)__builtin_bit_cast(_Float16, (unsigned short)(d >> 16));
    return c;
}

__device__ __forceinline__ f4 mfh(u4v a, u4v b, f4 c) {
    return __builtin_amdgcn_mfma_f32_16x16x32_f16(
        __builtin_bit_cast(h8, a), __builtin_bit_cast(h8, b), c, 0, 0, 0);
}

// scattered-read base: XOR-select over n, wid, and q-part
#define RD_SREP(B)                                                     \
    unsigned srep = 0;                                                 \
    srep ^= (n & 1u)   ? B.rdy[0] : 0u;                                \
    srep ^= (n & 2u)   ? B.rdy[1] : 0u;                                \
    srep ^= (n & 4u)   ? B.rdy[2] : 0u;                                \
    srep ^= (n & 8u)   ? B.rdy[3] : 0u;                                \
    srep ^= (wid & 1u) ? B.rdy[6] : 0u;                                \
    srep ^= (wid & 2u) ? B.rdy[7] : 0u;                                \
    srep ^= (wid & 4u) ? B.rdy[8] : 0u;                                \
    srep ^= (wid & 8u) ? B.rdy[9] : 0u;                                \
    srep ^= (q & 1u)   ? B.rde[4] : 0u;                                \
    srep ^= (q & 2u)   ? B.rde[8] : 0u;

// ---- fused pair 0: layer-0 wires 0-7, clean per-thread b128 read/write ----
__device__ __forceinline__ void mfma_pair0(char* __restrict__ lds, const float* __restrict__ gm,
                                           unsigned* __restrict__ atab, const unsigned bnq) {
    const unsigned tid = threadIdx.x;
    const unsigned lane = tid & 63u;
    const unsigned n = lane & 15u, q = lane >> 4;

    __syncthreads();   // staging visible

    if (tid < 512) {
        const unsigned idx = tid & 255u;
        const unsigned m = idx >> 4, ein = idx & 15u;
        const int gbase = (tid < 256) ? 0 : 4;
        float wr = 1.f, wi = 0.f;
        #pragma unroll
        for (int j = 0; j < 4; ++j) {
            const unsigned mj = (m >> j) & 1u, ej = (ein >> j) & 1u;
            const float ur = gm[(gbase + j) * 8 + (int)(mj * 4u + ej * 2u)];
            const float ui = gm[(gbase + j) * 8 + (int)(mj * 4u + ej * 2u) + 1];
            const float nr = wr * ur - wi * ui;
            const float ni = wr * ui + wi * ur;
            wr = nr; wi = ni;
        }
        const unsigned o = m * 16u + (ein ^ (m & 12u));
        unsigned* __restrict__ tab = atab + ((tid < 256) ? 0 : 512);
        tab[o]        = pk_rn(wr, -wi);   // (Wr, -Wi)
        tab[256 + o]  = pk_rn(wi, wr);    // (Wi,  Wr)
    }

    u4v bfr[4];
    #pragma unroll
    for (int t = 0; t < 4; ++t) {
        bfr[t] = *(const u4v*)(lds + (bnq ^ TILE_OFF[t]));
    }

    __syncthreads();   // tables ready

    const unsigned tix = (n << 4) + (((q << 2) ^ (n & 12u)));
    const u4v War = *(const u4v*)&atab[tix];
    const u4v Wai = *(const u4v*)&atab[256 + tix];
    const u4v Wbr = *(const u4v*)&atab[512 + tix];
    const u4v Wbi = *(const u4v*)&atab[768 + tix];

    #pragma unroll
    for (int t = 0; t < 4; ++t) {
        f4 dr = {0.f, 0.f, 0.f, 0.f};
        f4 di = {0.f, 0.f, 0.f, 0.f};
        dr = mfh(bfr[t], War, dr);
        di = mfh(bfr[t], Wai, di);
        u4v pb;
        pb.x = pk_rn(dr.x, di.x);
        pb.y = pk_rn(dr.y, di.y);
        pb.z = pk_rn(dr.z, di.z);
        pb.w = pk_rn(dr.w, di.w);
        f4 ar = {0.f, 0.f, 0.f, 0.f};
        f4 ai = {0.f, 0.f, 0.f, 0.f};
        ar = mfh(Wbr, pb, ar);
        ai = mfh(Wbi, pb, ai);
        u4v s;
        s.x = pk_rn(ar.x, ai.x);
        s.y = pk_rn(ar.y, ai.y);
        s.z = pk_rn(ar.z, ai.z);
        s.w = pk_rn(ar.w, ai.w);
        *(u4v*)(lds + (bnq ^ TILE_OFF[t])) = s;
    }
}

// ---- fused pair 2: layer-1 wires 0-7, scattered reads from F[3] ----
__device__ __forceinline__ void mfma_pair2(char* __restrict__ lds, const float* __restrict__ gm,
                                           unsigned* __restrict__ atab, const unsigned bnq) {
    constexpr Pair2P P = PL.p2;
    const unsigned tid = threadIdx.x;
    const unsigned lane = tid & 63u, wid = tid >> 6;
    const unsigned n = lane & 15u, q = lane >> 4;

    __syncthreads();   // prev batch stores visible; prev atab reads done

    // build Wa -> atab[0..511], Wb -> atab[512..1023]
    if (tid < 512) {
        const unsigned idx = tid & 255u;
        const unsigned m = idx >> 4, ein = idx & 15u;
        float wr = 1.f, wi = 0.f;
        #pragma unroll
        for (int j = 0; j < 4; ++j) {
            const int gi = (tid < 256) ? P.gA[j] : P.gB[j];
            const unsigned mj = (m >> j) & 1u, ej = (ein >> j) & 1u;
            const float ur = gm[gi * 8 + (int)(mj * 4u + ej * 2u)];
            const float ui = gm[gi * 8 + (int)(mj * 4u + ej * 2u) + 1];
            const float nr = wr * ur - wi * ui;
            const float ni = wr * ui + wi * ur;
            wr = nr; wi = ni;
        }
        const unsigned o = m * 16u + (ein ^ (m & 12u));
        unsigned* __restrict__ tab = atab + ((tid < 256) ? 0 : 512);
        tab[o]        = pk_rn(wr, -wi);
        tab[256 + o]  = pk_rn(wi, wr);
    }

    // scattered reads: fragment A[r=eB (n)][k=eA (q*4+dword)] from F[3]
    u4v bfr[4];
    {
        RD_SREP(P)
        #pragma unroll
        for (int t = 0; t < 4; ++t) {
            const unsigned st = srep ^ ((t & 1) ? P.rdy[4] : 0u) ^ ((t & 2) ? P.rdy[5] : 0u);
            const unsigned c0 = *(const unsigned*)(lds + st);
            const unsigned c1 = *(const unsigned*)(lds + (st ^ P.rde[1]));
            const unsigned c2 = *(const unsigned*)(lds + (st ^ P.rde[2]));
            const unsigned c3 = *(const unsigned*)(lds + (st ^ P.rde[3]));
            u4v v; v.x = c0; v.y = c1; v.z = c2; v.w = c3;
            bfr[t] = v;
        }
    }

    __syncthreads();   // reads done (WAR) + tables ready

    const unsigned tix = (n << 4) + (((q << 2) ^ (n & 12u)));
    const u4v War = *(const u4v*)&atab[tix];         // stage-1 B-operand
    const u4v Wai = *(const u4v*)&atab[256 + tix];
    const u4v Wbr = *(const u4v*)&atab[512 + tix];   // stage-2 A-operand
    const u4v Wbi = *(const u4v*)&atab[768 + tix];

    #pragma unroll
    for (int t = 0; t < 4; ++t) {
        // stage 1: D1 = (Wa * M)^T
        f4 dr = {0.f, 0.f, 0.f, 0.f};
        f4 di = {0.f, 0.f, 0.f, 0.f};
        dr = mfh(bfr[t], War, dr);
        di = mfh(bfr[t], Wai, di);
        u4v pb;
        pb.x = pk_rn(dr.x, di.x);
        pb.y = pk_rn(dr.y, di.y);
        pb.z = pk_rn(dr.z, di.z);
        pb.w = pk_rn(dr.w, di.w);
        // stage 2: D2 = Wb * D1 -> clean writer-frame store (FQ2 semantics)
        f4 ar = {0.f, 0.f, 0.f, 0.f};
        f4 ai = {0.f, 0.f, 0.f, 0.f};
        ar = mfh(Wbr, pb, ar);
        ai = mfh(Wbi, pb, ai);
        u4v s;
        s.x = pk_rn(ar.x, ai.x);
        s.y = pk_rn(ar.y, ai.y);
        s.z = pk_rn(ar.z, ai.z);
        s.w = pk_rn(ar.w, ai.w);
        *(u4v*)(lds + (bnq ^ TILE_OFF[t])) = s;
    }
}

template <int BI>
__device__ __forceinline__ void mfma_batch(char* __restrict__ lds, const float* __restrict__ gm,
                                           unsigned* __restrict__ atab, const unsigned bnq) {
    constexpr BatchP B = PL.b[BI];
    const unsigned tid = threadIdx.x;
    const unsigned lane = tid & 63u, wid = tid >> 6;
    const unsigned n = lane & 15u, q = lane >> 4;

    __syncthreads();   // prev batch stores visible; prev atab reads done

    // ---- A-table build (threads 0..255), f16 HI-ONLY, SWIZZLED layout ----
    if (tid < 256) {
        const unsigned m = tid >> 4, ein = tid & 15u;
        float wr = 1.f, wi = 0.f;
        #pragma unroll
        for (int j = 0; j < 4; ++j) {
            if (j < B.ngates) {
                const unsigned mj = (m >> j) & 1u, ej = (ein >> j) & 1u;
                const float ur = gm[B.gidx[j] * 8 + (int)(mj * 4u + ej * 2u)];
                const float ui = gm[B.gidx[j] * 8 + (int)(mj * 4u + ej * 2u) + 1];
                const float nr = wr * ur - wi * ui;
                const float ni = wr * ui + wi * ur;
                wr = nr; wi = ni;
            }
        }
        if (B.ngates < 4 && (((m ^ ein) >> B.ngates) != 0u)) { wr = 0.f; wi = 0.f; }
        const unsigned o = m * 16u + (ein ^ (m & 12u));
        atab[o]        = pk_rn(wr, -wi);   // (Wr, -Wi) -> real output
        atab[256 + o]  = pk_rn(wi, wr);    // (Wi,  Wr) -> imag output
    }

    // ---- phase A: pure loads (state IS the f16 B-fragment) ----
    u4v bfr[4];
    {
        RD_SREP(B)
        #pragma unroll
        for (int t = 0; t < 4; ++t) {
            const unsigned st = srep ^ ((t & 1) ? B.rdy[4] : 0u) ^ ((t & 2) ? B.rdy[5] : 0u);
            const unsigned c0 = *(const unsigned*)(lds + st);
            const unsigned c1 = *(const unsigned*)(lds + (st ^ B.rde[1]));
            const unsigned c2 = *(const unsigned*)(lds + (st ^ B.rde[2]));
            const unsigned c3 = *(const unsigned*)(lds + (st ^ B.rde[3]));
            u4v v; v.x = c0; v.y = c1; v.z = c2; v.w = c3;
            bfr[t] = v;
        }
    }

    __syncthreads();   // all reads done + atab ready

    // ---- phase B: 2 mfma/tile + RNE pack + 1 clean b128 store/tile ----
    const unsigned tix = (n << 4) + (((q << 2) ^ (n & 12u)));
    const u4v A0 = *(const u4v*)&atab[tix];
    const u4v A1 = *(const u4v*)&atab[256 + tix];

    #pragma unroll
    for (int t = 0; t < 4; ++t) {
        f4 ar = {0.f, 0.f, 0.f, 0.f};
        f4 ai = {0.f, 0.f, 0.f, 0.f};
        ar = mfh(A0, bfr[t], ar);
        ai = mfh(A1, bfr[t], ai);
        u4v s;
        s.x = pk_rn(ar.x, ai.x);
        s.y = pk_rn(ar.y, ai.y);
        s.z = pk_rn(ar.z, ai.z);
        s.w = pk_rn(ar.w, ai.w);
        *(u4v*)(lds + (bnq ^ TILE_OFF[t])) = s;
    }
}

// complex 2x2 butterfly
#define BFC(A, B_, ua, ub) { const float2 t0 = A, t1 = B_; \
    A.x  = ua.x * t0.x - ua.y * t0.y + ua.z * t1.x - ua.w * t1.y; \
    A.y  = ua.x * t0.y + ua.y * t0.x + ua.z * t1.y + ua.w * t1.x; \
    B_.x = ub.x * t0.x - ub.y * t0.y + ub.z * t1.x - ub.w * t1.y; \
    B_.y = ub.x * t0.y + ub.y * t0.x + ub.z * t1.y + ub.w * t1.x; }

__device__ __forceinline__ float tail_batch(char* __restrict__ lds, const float* __restrict__ gm,
                                            const float* __restrict__ g_hw) {
    constexpr BatchP B = PL.b[11];   // ngates == 2
    const unsigned tid = threadIdx.x;
    const unsigned lane = tid & 63u, wid = tid >> 6;
    const unsigned n = lane & 15u, q = lane >> 4;
    __syncthreads();
    const f4 u0a = *(const f4*)&gm[B.gidx[0] * 8];
    const f4 u0b = *(const f4*)&gm[B.gidx[0] * 8 + 4];
    const f4 u1a = *(const f4*)&gm[B.gidx[1] * 8];
    const f4 u1b = *(const f4*)&gm[B.gidx[1] * 8 + 4];
    float hwv[NW];
    #pragma unroll
    for (int w = 0; w < NW; ++w) hwv[w] = g_hw[w];
    float acc = 0.f;
    RD_SREP(B)
    #pragma unroll
    for (int t = 0; t < 4; ++t) {
        const unsigned st = srep ^ ((t & 1) ? B.rdy[4] : 0u) ^ ((t & 2) ? B.rdy[5] : 0u);
        float2 c0 = up(*(const unsigned*)(lds + st));
        float2 c1 = up(*(const unsigned*)(lds + (st ^ B.rde[1])));
        float2 c2 = up(*(const unsigned*)(lds + (st ^ B.rde[2])));
        float2 c3 = up(*(const unsigned*)(lds + (st ^ B.rde[3])));
        BFC(c0, c1, u0a, u0b)  BFC(c2, c3, u0a, u0b)   // gate 0: slot bit 0
        BFC(c0, c2, u1a, u1b)  BFC(c1, c3, u1a, u1b)   // gate 1: slot bit 1
        const float p0 = c0.x * c0.x + c0.y * c0.y;
        const float p1 = c1.x * c1.x + c1.y * c1.y;
        const float p2 = c2.x * c2.x + c2.y * c2.y;
        const float p3 = c3.x * c3.x + c3.y * c3.y;
        const float sa = p0 + p1, sb = p0 - p1, sc = p2 + p3, sd = p2 - p3;
        const float W4[4] = {sa + sc, sb + sd, sa - sc, sb - sd};
        const unsigned y = (wid << 6) | ((unsigned)t << 4) | n;
        const unsigned key = y | (q << 10);
        #pragma unroll
        for (int w = 0; w < NW; ++w) {
            const unsigned sg = ((unsigned)__popc(key & PL.ykey[w])) << 31;
            const float s = __uint_as_float(__float_as_uint(hwv[w]) ^ sg);
            acc += W4[PL.zsel[w]] * s;
        }
    }
    return acc;
}

__global__ __launch_bounds__(BLOCK, 8) void qsim_kernel(
    const float* __restrict__ g_sr, const float* __restrict__ g_si,
    const float* __restrict__ g_params, const float* __restrict__ g_hw,
    const float* __restrict__ g_hb, float* __restrict__ g_out)
{
    extern __shared__ char lds[];                    // 16384 packed-f16 amps (64 KiB)
    __shared__ __align__(16) float gm[NGAT * 8];
    __shared__ __align__(16) unsigned atab[1024];    // Wa(512)+Wb(512) for pairs; batches use [0..511]
    __shared__ float red[BLOCK / 64];

    const unsigned tid = threadIdx.x;
    const int b = blockIdx.x;
    const float* __restrict__ srcr = g_sr + (size_t)b * DIM;
    const float* __restrict__ srci = g_si + (size_t)b * DIM;

    // ---- gate matrices U = RZ @ RY @ RX ----
    if (tid < NGAT) {
        const float tx = g_params[tid * 3 + 0];
        const float ty = g_params[tid * 3 + 1];
        const float tz = g_params[tid * 3 + 2];
        const float cx = cosf(0.5f * tx), sx = sinf(0.5f * tx);
        const float cy = cosf(0.5f * ty), sy = sinf(0.5f * ty);
        const float cz = cosf(0.5f * tz), sz = sinf(0.5f * tz);
        const float a00r = cy * cx,  a00i = sy * sx;
        const float a01r = -sy * cx, a01i = -cy * sx;
        const float a10r = sy * cx,  a10i = -cy * sx;
        const float a11r = cy * cx,  a11i = -sy * sx;
        gm[tid * 8 + 0] = cz * a00r + sz * a00i;
        gm[tid * 8 + 1] = cz * a00i - sz * a00r;
        gm[tid * 8 + 2] = cz * a01r + sz * a01i;
        gm[tid * 8 + 3] = cz * a01i - sz * a01r;
        gm[tid * 8 + 4] = cz * a10r - sz * a10i;
        gm[tid * 8 + 5] = cz * a10i + sz * a10r;
        gm[tid * 8 + 6] = cz * a11r - sz * a11i;
        gm[tid * 8 + 7] = cz * a11i + sz * a11r;
    }

    // writer-frame base for this thread (computed ONCE; T twist folded in).
    const unsigned lane0 = tid & 63u, wid0 = tid >> 6;
    const unsigned n0 = lane0 & 15u, q0 = lane0 >> 4;
    unsigned twv = 0;
    #pragma unroll
    for (int k = 0; k < 4; ++k) twv ^= ((n0 >> k) & 1u) ? PL.tw[k] : 0u;
    #pragma unroll
    for (int k = 0; k < 4; ++k) twv ^= ((wid0 >> k) & 1u) ? PL.tw[6 + k] : 0u;
    const unsigned bnq = ((wid0 << 10) ^ (n0 << 4) ^ (q0 << 2) ^ twv) << 2;

    // ---- staging: global fp32 -> packed f16 in (T o FIN^-1) layout ----
    unsigned bb = 0;
    #pragma unroll
    for (int k = 0; k < 10; ++k) bb ^= ((tid >> k) & 1u) ? PL.stB[k + 2] : 0u;
    #pragma unroll
    for (int it = 0; it < 4; ++it) {
        const int x = (int)tid * 4 + it * 4096;
        const f4 r4 = *(const f4*)(srcr + x);
        const f4 i4 = *(const f4*)(srci + x);
        const unsigned base = bb ^ ((it & 1) ? PL.stB[12] : 0u) ^ ((it & 2) ? PL.stB[13] : 0u);
        *(unsigned*)(lds + base) = pk_rn(r4.x, i4.x);
        *(unsigned*)(lds + (base ^ PL.stB[0])) = pk_rn(r4.y, i4.y);
        *(unsigned*)(lds + (base ^ PL.stB[1])) = pk_rn(r4.z, i4.z);
        *(unsigned*)(lds + (base ^ (PL.stB[0] ^ PL.stB[1]))) = pk_rn(r4.w, i4.w);
    }

    mfma_pair0(lds, gm, atab, bnq);      // fused batches 0+1 (layer 0, wires 0-7)
    mfma_batch<2>(lds, gm, atab, bnq);
    mfma_batch<3>(lds, gm, atab, bnq);
    mfma_pair2(lds, gm, atab, bnq);      // fused batches 4+5 (layer 1, wires 0-7)
    mfma_batch<6>(lds, gm, atab, bnq);
    mfma_batch<7>(lds, gm, atab, bnq);
    mfma_batch<8>(lds, gm, atab, bnq);
    mfma_batch<9>(lds, gm, atab, bnq);
    mfma_batch<10>(lds, gm, atab, bnq);

    float acc = tail_batch(lds, gm, g_hw);

    // ---- reduce ----
    #pragma unroll
    for (int off = 32; off > 0; off >>= 1) acc += __shfl_down(acc, off);
    const int lane = tid & 63, wid = tid >> 6;
    if (lane == 0) red[wid] = acc;
    __syncthreads();
    if (tid == 0) {
        float s = 0.0f;
        #pragma unroll
        for (int k = 0; k < BLOCK / 64; ++k) s += red[k];
        g_out[b] = s + g_hb[0];
    }
}

extern "C" void kernel_launch(void* const* d_in, const int* in_sizes, int n_in,
                              void* d_out, int out_size, void* d_ws, size_t ws_size,
                              hipStream_t stream) {
    const float* sr = (const float*)d_in[0];
    const float* si = (const float*)d_in[1];
    const float* vp = (const float*)d_in[2];
    const float* hw = (const float*)d_in[3];
    const float* hb = (const float*)d_in[4];
    float* out = (float*)d_out;

    dim3 grid(out_size);          // 1024 batch elements, one block each
    dim3 block(BLOCK);
    size_t shmem = (size_t)DIM * 4;  // 64 KiB dynamic LDS (packed f16 amps)
    qsim_kernel<<<grid, block, shmem, stream>>>(sr, si, vp, hw, hb, out);
}